// Round 10
// baseline (711.383 us; speedup 1.0000x reference)
//
#include <hip/hip_runtime.h>
#include <hip/hip_cooperative_groups.h>

namespace cg = cooperative_groups;

// ---------------------------------------------------------------------------
// InterpretableFusion v10 — ONE cooperative kernel, 3 phases, grid.sync.
//   scores[n,m] = ( x.(G_m l) + x.v_m + l.u_m + c_m )/sqrt(D)
//   G_m = Wq^T Wk_m (bf16, 2 MB, L2-resident in phase 2).
// v9 -> v10: unified VGPR+AGPR must fit 128 to get 4 waves/SIMD (2 blk/CU):
//   - jh=2 GEMM split (kacc[4][2]): halves A ds_read traffic vs v9's jp=4
//     (1024 -> 512 ds_read_b128/wave/tile) and keeps live ~115 regs.
//   - write-through staging (no tmp batch arrays): -16 regs.
//   - phase 3 walks the SAME tiles the block staged in phase 2 (L2-warm),
//     weights cached in LDS, flat coalesced indexing.
// ---------------------------------------------------------------------------

typedef __bf16 bf16x8 __attribute__((ext_vector_type(8)));
typedef __bf16 bf16x4 __attribute__((ext_vector_type(4)));
typedef float  f32x4  __attribute__((ext_vector_type(4)));

#define NTOK 50000
#define DDIM 512
#define NMOD 4
#define BN   64
#define NBLK ((NTOK + BN - 1) / BN)        // 782
#define WOFF ((size_t)NTOK * DDIM)         // weights region (float offset)
#define UOFF 600000                        // u[m][d]
#define VOFF 610000                        // v[m][d]
#define COFF 620000                        // c[m]
#define FOFF 620004                        // 32 bias-nonzero flags
#define SCALE 0.044194173824159216f        // 1/sqrt(512)

// row stride 1024B (512 bf16); XOR byte bits 4-6 with row&7 (guide §6 G4)
#define SWZ(r, b) ((((r) * 1024) + (b)) ^ (((r) & 7) << 4))

__global__ __launch_bounds__(512, 2) void mono_kernel(
    const float* __restrict__ gnn, const float* __restrict__ lat,
    const float* __restrict__ Wq, const float* __restrict__ bq,
    const float* __restrict__ Wk, const float* __restrict__ bk,
    float* __restrict__ out)
{
    __shared__ __align__(16) char smem[68608];
    const int tid = threadIdx.x;
    const int bid = blockIdx.x;
    const int ngrid = gridDim.x;
    cg::grid_group gg = cg::this_grid();

    // ========== phase 1: G = Wq^T Wk_m (512 subtiles of 64x32) + u,v,c ======
    {
        float* ldsQ = (float*)smem;            // [64][64] fp32
        float* ldsK = (float*)(smem + 16384);  // [64][32] fp32
        for (int gb = bid; gb < 512; gb += ngrid) {
            const int m = gb >> 7, ib = gb & 127, dblk = ib >> 4, dpb = ib & 15;
            const int dl = tid >> 3, c8 = tid & 7;
            f32x4 ac = {0.f, 0.f, 0.f, 0.f};
            for (int e0 = 0; e0 < DDIM; e0 += 64) {
                __syncthreads();
                #pragma unroll
                for (int it = 0; it < 2; ++it) {
                    int idx = it * 512 + tid, e = idx >> 4, c4 = idx & 15;
                    *(f32x4*)&ldsQ[e * 64 + c4 * 4] =
                        *(const f32x4*)&Wq[(size_t)(e0 + e) * DDIM + dblk * 64 + c4 * 4];
                }
                {
                    int e = tid >> 3, c4 = tid & 7;
                    *(f32x4*)&ldsK[e * 32 + c4 * 4] =
                        *(const f32x4*)&Wk[((size_t)m * DDIM + e0 + e) * DDIM + dpb * 32 + c4 * 4];
                }
                __syncthreads();
                for (int e = 0; e < 64; ++e) {
                    float wq = ldsQ[e * 64 + dl];
                    ac += wq * *(const f32x4*)&ldsK[e * 32 + c8 * 4];
                }
            }
            __bf16* Gw = (__bf16*)out;
            bf16x4 o;
            o[0] = (__bf16)ac[0]; o[1] = (__bf16)ac[1];
            o[2] = (__bf16)ac[2]; o[3] = (__bf16)ac[3];
            *(bf16x4*)(Gw + ((size_t)m * DDIM + dblk * 64 + dl) * DDIM
                       + dpb * 32 + c8 * 4) = o;
        }

        if (bid < 32) {                        // u, v, c + bias flags
            __syncthreads();                   // own block's LDS reads done
            float* up = (float*)smem;          // [4][64]
            float* vp = (float*)smem + 256;    // [4][64]
            const int m2 = bid >> 3, dc = bid & 7;
            if (tid < 256) {
                const int dl2 = tid & 63, eg = tid >> 6;
                const int d = dc * 64 + dl2;
                float us = 0.f, vs = 0.f;
                #pragma unroll 4
                for (int e = eg * 128; e < eg * 128 + 128; ++e) {
                    us += Wk[((size_t)m2 * DDIM + e) * DDIM + d] * bq[e];
                    vs += Wq[(size_t)e * DDIM + d] * bk[m2 * DDIM + e];
                }
                up[eg * 64 + dl2] = us; vp[eg * 64 + dl2] = vs;
            }
            __syncthreads();
            if (tid < 64) {
                const int d = dc * 64 + tid;
                float uu = up[tid] + up[64+tid] + up[128+tid] + up[192+tid];
                float vv = vp[tid] + vp[64+tid] + vp[128+tid] + vp[192+tid];
                out[UOFF + m2 * DDIM + d] = uu;
                out[VOFF + m2 * DDIM + d] = vv;
                float cp = 0.f;
                if (dc == 0) {
                    #pragma unroll
                    for (int i = 0; i < 8; ++i)
                        cp += bq[tid * 8 + i] * bk[m2 * DDIM + tid * 8 + i];
                    #pragma unroll
                    for (int msk = 1; msk < 64; msk <<= 1)
                        cp += __shfl_xor(cp, msk, 64);
                    if (tid == 0) out[COFF + m2] = cp;
                }
                unsigned long long anyb =
                    __ballot((uu != 0.f) || (vv != 0.f) || (cp != 0.f));
                if (tid == 0) out[FOFF + bid] = anyb ? 1.f : 0.f;  // always written
            }
        }
    }
    gg.sync();   // G/u/v/c/flags visible device-wide

    // ========== phase 2: scores -> softmax -> weights ==========
    {
        __bf16* tile  = (__bf16*)smem;             // 64 KiB (X once, then L_m)
        float* s_part = (float*)(smem + 65536);    // [8][64]
        float* s_all  = (float*)(smem + 67584);    // [64][4]
        const __bf16* Gb = (const __bf16*)out;
        const int lane = tid & 63, w = tid >> 6;
        const int g = (lane >> 4) & 3, c = lane & 15;

        bool bias = false;
        for (int i2 = 0; i2 < 32; ++i2) bias |= (out[FOFF + i2] != 0.f);

        for (int t = bid; t < NBLK; t += ngrid) {
            const int row0 = t * BN;
            const int vrows = (NTOK - row0 < BN) ? (NTOK - row0) : BN;

            // write-through staging: no batch arrays (register relief);
            // the compiler hoists the independent nt loads as regs allow.
            auto stage = [&](const float* src, int rsF) {
                #pragma unroll
                for (int i = 0; i < 16; ++i) {
                    int f4 = i * 512 + tid, r = f4 >> 7, c4 = f4 & 127;
                    f32x4 v = (r < vrows)
                        ? __builtin_nontemporal_load(
                              (const f32x4*)(src + (size_t)r * rsF + c4 * 4))
                        : (f32x4){0.f, 0.f, 0.f, 0.f};
                    bf16x4 o;
                    o[0] = (__bf16)v[0]; o[1] = (__bf16)v[1];
                    o[2] = (__bf16)v[2]; o[3] = (__bf16)v[3];
                    *(bf16x4*)((char*)tile + SWZ(r, c4 * 8)) = o;
                }
            };

            // X tile -> xbf regs (rows rt*16+g*4+reg, cols w*64+j*16+c)
            stage(gnn + (size_t)row0 * DDIM, DDIM);
            __syncthreads();
            bf16x4 xbf[4][4];
            #pragma unroll
            for (int rt = 0; rt < 4; ++rt)
                #pragma unroll
                for (int j = 0; j < 4; ++j) {
                    bf16x4 tq;
                    #pragma unroll
                    for (int reg = 0; reg < 4; ++reg) {
                        int r = rt * 16 + g * 4 + reg, col = w * 64 + j * 16 + c;
                        tq[reg] = *(const __bf16*)((const char*)tile + SWZ(r, col * 2));
                    }
                    xbf[rt][j] = tq;
                }

            for (int m = 0; m < NMOD; ++m) {
                __syncthreads();   // xbf-extract / prev-m tile & s_part reads done
                stage(lat + ((size_t)row0 * NMOD + m) * DDIM, NMOD * DDIM);
                __syncthreads();

                float p[4][4];
                if (bias) {   // general path (u,v != 0); skipped for these inputs
                    float u4[4], v4[4];
                    #pragma unroll
                    for (int j = 0; j < 4; ++j) {
                        int col = w * 64 + j * 16 + c;
                        u4[j] = out[UOFF + m * DDIM + col];
                        v4[j] = out[VOFF + m * DDIM + col];
                    }
                    #pragma unroll
                    for (int rt = 0; rt < 4; ++rt)
                        #pragma unroll
                        for (int reg = 0; reg < 4; ++reg) {
                            int r = rt * 16 + g * 4 + reg;
                            float tacc = 0.f;
                            #pragma unroll
                            for (int j = 0; j < 4; ++j) {
                                int col = w * 64 + j * 16 + c;
                                float lv = (float)*(const __bf16*)((const char*)tile +
                                                                   SWZ(r, col * 2));
                                tacc += (float)xbf[rt][j][reg] * v4[j] + lv * u4[j];
                            }
                            p[rt][reg] = tacc;
                        }
                } else {
                    #pragma unroll
                    for (int rt = 0; rt < 4; ++rt)
                        #pragma unroll
                        for (int reg = 0; reg < 4; ++reg)
                            p[rt][reg] = 0.f;
                }

                // z = G_m l via MFMA: 2 jh-passes (kacc[4][2] = 32 regs;
                // each A-fragment feeds 2 MFMAs -> half of v9's ds_reads)
                const __bf16* Gm = Gb + (size_t)m * DDIM * DDIM;
                #pragma unroll
                for (int jh = 0; jh < 2; ++jh) {
                    f32x4 kacc[4][2];
                    #pragma unroll
                    for (int rt = 0; rt < 4; ++rt) {
                        kacc[rt][0] = (f32x4){0.f, 0.f, 0.f, 0.f};
                        kacc[rt][1] = (f32x4){0.f, 0.f, 0.f, 0.f};
                    }
                    const __bf16* gp0 = Gm + (size_t)(w * 64 + (jh * 2 + 0) * 16 + c) * DDIM + g * 8;
                    const __bf16* gp1 = Gm + (size_t)(w * 64 + (jh * 2 + 1) * 16 + c) * DDIM + g * 8;
                    for (int k0 = 0; k0 < DDIM; k0 += 32) {
                        bf16x8 b0 = *(const bf16x8*)(gp0 + k0);
                        bf16x8 b1 = *(const bf16x8*)(gp1 + k0);
                        bf16x8 a[4];
                        const int kb = k0 * 2 + g * 16;
                        #pragma unroll
                        for (int rt = 0; rt < 4; ++rt)
                            a[rt] = *(const bf16x8*)((const char*)tile +
                                                     SWZ(rt * 16 + c, kb));
                        #pragma unroll
                        for (int rt = 0; rt < 4; ++rt) {
                            kacc[rt][0] = __builtin_amdgcn_mfma_f32_16x16x32_bf16(
                                a[rt], b0, kacc[rt][0], 0, 0, 0);
                            kacc[rt][1] = __builtin_amdgcn_mfma_f32_16x16x32_bf16(
                                a[rt], b1, kacc[rt][1], 0, 0, 0);
                        }
                    }
                    #pragma unroll
                    for (int rt = 0; rt < 4; ++rt)
                        #pragma unroll
                        for (int reg = 0; reg < 4; ++reg)
                            p[rt][reg] += (float)xbf[rt][jh * 2 + 0][reg] * kacc[rt][0][reg]
                                        + (float)xbf[rt][jh * 2 + 1][reg] * kacc[rt][1][reg];
                    __builtin_amdgcn_sched_barrier(0);  // no cross-pass fusion
                }

                // reduce over 16 c-lanes, then across 8 waves via LDS
                #pragma unroll
                for (int msk = 1; msk < 16; msk <<= 1)
                    #pragma unroll
                    for (int rt = 0; rt < 4; ++rt)
                        #pragma unroll
                        for (int reg = 0; reg < 4; ++reg)
                            p[rt][reg] += __shfl_xor(p[rt][reg], msk, 64);
                if (c == 0) {
                    #pragma unroll
                    for (int rt = 0; rt < 4; ++rt)
                        #pragma unroll
                        for (int reg = 0; reg < 4; ++reg)
                            s_part[w * 64 + rt * 16 + g * 4 + reg] = p[rt][reg];
                }
                __syncthreads();
                if (tid < BN) {
                    float s = 0.f;
                    #pragma unroll
                    for (int ww = 0; ww < 8; ++ww) s += s_part[ww * 64 + tid];
                    s_all[tid * 4 + m] = s + out[COFF + m];
                }
            }

            if (tid < BN && row0 + tid < NTOK) {
                float e0 = __expf(s_all[tid*4+0] * SCALE), e1 = __expf(s_all[tid*4+1] * SCALE),
                      e2 = __expf(s_all[tid*4+2] * SCALE), e3 = __expf(s_all[tid*4+3] * SCALE);
                float iz = 1.f / (e0 + e1 + e2 + e3);
                f32x4 wv = {e0 * iz, e1 * iz, e2 * iz, e3 * iz};
                *(f32x4*)(out + WOFF + (size_t)(row0 + tid) * 4) = wv;
            }
        }
    }
    gg.sync();   // weights visible; G/u/v/c/flags region now dead

    // ========== phase 3: fused = sum_m w_m L_m (same tiles as phase 2 ==========
    //            -> lat rows L2-warm in this block's XCD; coalesced flat walk)
    {
        f32x4* wlds = (f32x4*)smem;                // [64] weights cache
        for (int t = bid; t < NBLK; t += ngrid) {
            const int row0 = t * BN;
            __syncthreads();                       // prev-t wlds reads done
            if (tid < BN)
                wlds[tid] = *(const f32x4*)(out + WOFF + (size_t)(row0 + tid) * 4);
            __syncthreads();
            #pragma unroll 4
            for (int it = 0; it < 16; ++it) {
                int f4 = it * 512 + tid, r = f4 >> 7, c4 = f4 & 127;
                const int row = row0 + r;
                if (row < NTOK) {
                    f32x4 w4 = wlds[r];
                    f32x4 acc = {0.f, 0.f, 0.f, 0.f};
                    #pragma unroll
                    for (int m = 0; m < NMOD; ++m) {
                        f32x4 v = __builtin_nontemporal_load(
                            (const f32x4*)(lat + ((size_t)row * NMOD + m) * DDIM + c4 * 4));
                        acc += w4[m] * v;
                    }
                    __builtin_nontemporal_store(acc,
                        (f32x4*)(out + (size_t)row * DDIM + c4 * 4));
                }
            }
        }
    }
}

extern "C" void kernel_launch(void* const* d_in, const int* in_sizes, int n_in,
                              void* d_out, int out_size, void* d_ws, size_t ws_size,
                              hipStream_t stream)
{
    const float* gnn = (const float*)d_in[0];   // [N, D]
    const float* lat = (const float*)d_in[1];   // [N, M, D]
    const float* Wq  = (const float*)d_in[2];   // [D, D]
    const float* bq  = (const float*)d_in[3];   // [D]
    const float* Wk  = (const float*)d_in[4];   // [M, D, D]
    const float* bk  = (const float*)d_in[5];   // [M, D]
    float* out = (float*)d_out;                 // fused [N,D] ++ weights [N,M]

    int maxb = 0;
    hipError_t oe = hipOccupancyMaxActiveBlocksPerMultiprocessor(
        &maxb, mono_kernel, 512, 0);
    const int ngrid = (oe == hipSuccess && maxb >= 2) ? 512 : 256;

    void* args[] = { (void*)&gnn, (void*)&lat, (void*)&Wq, (void*)&bq,
                     (void*)&Wk, (void*)&bk, (void*)&out };
    hipLaunchCooperativeKernel((const void*)mono_kernel, dim3(ngrid), dim3(512),
                               args, 0, stream);
}